// Round 5
// baseline (165.037 us; speedup 1.0000x reference)
//
#include <hip/hip_runtime.h>
#include <hip/hip_bf16.h>

#define NH 12
#define HD 64
#define NB 4
#define SEQ 2048
#define NP 768
#define LOG2E 1.44269504f
#define MASK_L2 14426.9504f   // 10000 * log2(e)

typedef __bf16 bf16x8 __attribute__((ext_vector_type(8)));
typedef __bf16 bf16x2 __attribute__((ext_vector_type(2)));
typedef float f32x2 __attribute__((ext_vector_type(2)));
typedef float f32x4 __attribute__((ext_vector_type(4)));
typedef float f32x16 __attribute__((ext_vector_type(16)));
typedef unsigned u32x4 __attribute__((ext_vector_type(4)));

static __device__ __forceinline__ bf16x8 load_bf16x8(const __bf16* p) {
    return *reinterpret_cast<const bf16x8*>(p);
}
static __device__ __forceinline__ float hw_exp2(float x) {
    return __builtin_amdgcn_exp2f(x);
}
// packed f32x2 -> bf16x2 (backend can select v_cvt_pk_bf16_f32 on gfx950)
static __device__ __forceinline__ unsigned cvtpk2(float lo, float hi) {
    f32x2 t; t[0] = lo; t[1] = hi;
    return __builtin_bit_cast(unsigned, __builtin_convertvector(t, bf16x2));
}
// async global->LDS, 16B per lane; LDS dest = uniform base + lane*16 (HW rule)
static __device__ __forceinline__ void async16(const __bf16* g, __bf16* l) {
    __builtin_amdgcn_global_load_lds(
        (const __attribute__((address_space(1))) unsigned*)(g),
        (__attribute__((address_space(3))) unsigned*)(l), 16, 0, 0);
}

// ---------------------------------------------------------------------------
// Kernel 0 (NEW): one-time weight transpose into B-frag-ready layout.
// Wt[proj][p][k] = W_proj[k][p] * qs   (bf16, 768x64 per proj, 295 KB total)
// bt[proj][p]    = bias_proj[p] * qs   (f32)
// Replaces the per-block wtileT LDS transpose that every one of the 128
// blockIdx.x blocks redundantly recomputed with ~8-way bank conflicts.
// ---------------------------------------------------------------------------
__global__ __launch_bounds__(256) void wprep_kernel(
    const float* __restrict__ Wq, const float* __restrict__ Wk,
    const float* __restrict__ Wv,
    const float* __restrict__ bq, const float* __restrict__ bk,
    const float* __restrict__ bv,
    __bf16* __restrict__ Wt, float* __restrict__ bt)
{
    const int blk  = blockIdx.x;       // 0..35
    const int proj = blk / 12;
    const int pb   = blk % 12;
    const float* W    = proj == 0 ? Wq : (proj == 1 ? Wk : Wv);
    const float* bias = proj == 0 ? bq : (proj == 1 ? bk : bv);
    const float qs    = (proj == 0) ? 0.125f * LOG2E : 1.0f;

    const int t  = threadIdx.x;
    const int p  = pb * 64 + (t >> 2);
    const int kc = (t & 3) * 16;

    bf16x8 o0, o1;
    #pragma unroll
    for (int i = 0; i < 8; ++i) {
        o0[i] = (__bf16)(W[(size_t)(kc + i) * NP + p] * qs);
        o1[i] = (__bf16)(W[(size_t)(kc + 8 + i) * NP + p] * qs);
    }
    __bf16* dst = Wt + ((size_t)proj * NP + p) * 64 + kc;
    *(bf16x8*)(dst)     = o0;
    *(bf16x8*)(dst + 8) = o1;

    if (t < 64) bt[proj * NP + pb * 64 + t] = bias[pb * 64 + t] * qs;
}

// ---------------------------------------------------------------------------
// Kernel 1 v2: QKV projection reading pre-transposed Wt. No W staging, no
// wtileT bank conflicts; ot double-buffered -> 1 barrier per tile (6 vs 12).
// Output layouts byte-identical to previous rounds.
// ---------------------------------------------------------------------------
__global__ __launch_bounds__(256) void qkv_kernel(
    const float* __restrict__ hidden,
    const __bf16* __restrict__ Wt, const float* __restrict__ bt,
    __bf16* __restrict__ Qw, __bf16* __restrict__ Kf, __bf16* __restrict__ Vf)
{
    __shared__ __bf16 ot[2][64][72];    // [buf][t][c]  18.4 KB

    const int tid  = threadIdx.x;
    const int lane = tid & 63;
    const int w    = tid >> 6;
    const int g    = lane >> 4;
    const int n    = lane & 15;
    const int n32  = lane & 31;
    const int hi   = lane >> 5;

    const int row0 = blockIdx.x * 64;
    const int gi   = blockIdx.y;          // 0..5
    const int b_   = row0 >> 11;
    const int t0   = row0 & (SEQ - 1);
    const int kb64 = t0 >> 6;

    const float* hrow = hidden + (size_t)(row0 + w * 16 + n) * HD + 8 * g;
    f32x4 h0 = *(const f32x4*)(hrow);
    f32x4 h1 = *(const f32x4*)(hrow + 4);
    f32x4 h2 = *(const f32x4*)(hrow + 32);
    f32x4 h3 = *(const f32x4*)(hrow + 36);
    bf16x8 a0, a1;
    #pragma unroll
    for (int j = 0; j < 4; ++j) {
        a0[j]     = (__bf16)h0[j];
        a0[j + 4] = (__bf16)h1[j];
        a1[j]     = (__bf16)h2[j];
        a1[j + 4] = (__bf16)h3[j];
    }

    for (int tt = 0; tt < 6; ++tt) {
        const int tile_id = gi * 6 + tt;       // 0..35
        const int proj    = tile_id / 12;
        const int head    = tile_id % 12;
        const int bh      = b_ * NH + head;

        const __bf16* wp = Wt + ((size_t)proj * NP + head * 64) * 64;
        const float*  bp = bt + proj * NP + head * 64;
        auto& otb = ot[tt & 1];

        #pragma unroll
        for (int dt = 0; dt < 4; ++dt) {
            const __bf16* wrow = wp + (size_t)(dt * 16 + n) * 64;
            const bf16x8 b0 = load_bf16x8(wrow + 8 * g);
            const bf16x8 b1 = load_bf16x8(wrow + 32 + 8 * g);
            f32x4 acc = {0.f, 0.f, 0.f, 0.f};
            acc = __builtin_amdgcn_mfma_f32_16x16x32_bf16(a0, b0, acc, 0, 0, 0);
            acc = __builtin_amdgcn_mfma_f32_16x16x32_bf16(a1, b1, acc, 0, 0, 0);
            const float bb = bp[dt * 16 + n];
            #pragma unroll
            for (int r = 0; r < 4; ++r)
                otb[w * 16 + 4 * g + r][dt * 16 + n] = (__bf16)(acc[r] + bb);
        }
        __syncthreads();   // otb complete; also fences prev reuse of this buf

        if (proj == 0) {
            __bf16* dst = Qw + ((size_t)bh * SEQ + t0 + w * 16) * HD;
            const int tr = lane >> 2;
            const int d0 = (lane & 3) * 16;
            *(bf16x8*)(dst + (size_t)tr * HD + d0)     = *(const bf16x8*)&otb[w * 16 + tr][d0];
            *(bf16x8*)(dst + (size_t)tr * HD + d0 + 8) = *(const bf16x8*)&otb[w * 16 + tr][d0 + 8];
        } else if (proj == 1) {
            __bf16* base = Kf + (size_t)bh * SEQ * HD + (size_t)kb64 * 4096;
            #pragma unroll
            for (int sub = 0; sub < 2; ++sub) {
                const bf16x8 fr = *(const bf16x8*)&otb[sub * 32 + n32][w * 16 + 8 * hi];
                *(bf16x8*)(base + (size_t)(w * 2 + sub) * 512 + lane * 8) = fr;
            }
        } else {
            __bf16* base = Vf + (size_t)bh * SEQ * HD + (size_t)kb64 * 4096;
            #pragma unroll
            for (int dsub = 0; dsub < 2; ++dsub) {
                bf16x8 v;
                #pragma unroll
                for (int j = 0; j < 8; ++j)
                    v[j] = otb[w * 16 + ((j & 3) + 8 * (j >> 2) + 4 * hi)][dsub * 32 + n32];
                *(bf16x8*)(base + (size_t)(w * 2 + dsub) * 512 + lane * 8) = v;
            }
        }
    }
}

// ---------------------------------------------------------------------------
// Kernel 2 v15: v14 pipeline with ALL s_setprio brackets removed. setprio is
// a scheduling barrier: it pinned the 10-MFMA S burst as an indivisible
// block, preventing the scheduler from interleaving exp(t-1) VALU into the
// MFMA shadow (why v14 == v13). Now the scheduler is free to interleave.
// ---------------------------------------------------------------------------
struct KVbuf {
    __bf16 k[2][4096];   // 16 KB
    __bf16 v[3][4096];   // 24 KB
};

union FlashLds {
    KVbuf s;                  // 40960 B
    float et[4][32][68];      // 34816 B (epilogue reuse)
};

static __device__ __forceinline__ int rot3(int x) { return x + 1 == 3 ? 0 : x + 1; }

// One pipelined iteration. KS = t&1 (K slot). STG: stage tile t+1. DOPV:
// run exp(t-1)+PV(t-1) from (sap,sbp) and v[vprev].
template<int KS, bool STG, bool DOPV>
static __device__ __forceinline__ void fbody(
    int t, int vprev, int vnext, int w, int lane, int n32,
    FlashLds* u, const __bf16* mdd, const __bf16* gsrc,
    const bf16x8 (&qf)[4], const bf16x8& qone,
    f32x16& sap, f32x16& sbp, f32x16& san, f32x16& sbn,
    f32x16& o0, f32x16& o1, f32x2& lsl2)
{
    if (STG) {
        __bf16* dst = (w < 2) ? &u->s.k[KS ^ 1][0] + (w & 1) * 2048
                              : &u->s.v[vnext][0] + (w & 1) * 2048;
        const __bf16* src = gsrc + (size_t)(t + 1) * 4096;
        #pragma unroll
        for (int c = 0; c < 4; ++c) async16(src + c * 512, dst + c * 512);
    }

    // K(t) fragments
    const __bf16* Kb = &u->s.k[KS][0];
    bf16x8 kca[4], kcb[4];
    #pragma unroll
    for (int d = 0; d < 4; ++d) {
        kca[d] = load_bf16x8(Kb + (2 * d) * 512 + lane * 8);
        kcb[d] = load_bf16x8(Kb + (2 * d + 1) * 512 + lane * 8);
    }
    const int kb = t << 6;
    bf16x8 maa, mab;
    #pragma unroll
    for (int j = 0; j < 8; ++j) { maa[j] = (__bf16)0.0f; mab[j] = (__bf16)0.0f; }
    maa[0] = mdd[kb + n32];
    mab[0] = mdd[kb + 32 + n32];

    // S(t) burst (new accumulators; prev set stays live for exp below)
    f32x16 z = {0,0,0,0,0,0,0,0,0,0,0,0,0,0,0,0};
    san = z; sbn = z;
    #pragma unroll
    for (int d = 0; d < 4; ++d)
        san = __builtin_amdgcn_mfma_f32_32x32x16_bf16(kca[d], qf[d], san, 0, 0, 0);
    san = __builtin_amdgcn_mfma_f32_32x32x16_bf16(maa, qone, san, 0, 0, 0);
    #pragma unroll
    for (int d = 0; d < 4; ++d)
        sbn = __builtin_amdgcn_mfma_f32_32x32x16_bf16(kcb[d], qf[d], sbn, 0, 0, 0);
    sbn = __builtin_amdgcn_mfma_f32_32x32x16_bf16(mab, qone, sbn, 0, 0, 0);

    if (DOPV) {
        const __bf16* Vb = &u->s.v[vprev][0];
        // half 0: exp(sap) -> P0,P1 ; PV chunks 0..3
        bf16x8 P0, P1;
        {
            u32x4 B0, B1;
            #pragma unroll
            for (int i = 0; i < 4; ++i) {
                float e0 = hw_exp2(sap[2 * i]),     e1 = hw_exp2(sap[2 * i + 1]);
                float f0 = hw_exp2(sap[8 + 2 * i]), f1 = hw_exp2(sap[8 + 2 * i + 1]);
                B0[i] = cvtpk2(e0, e1);
                B1[i] = cvtpk2(f0, f1);
                f32x2 acc; acc[0] = e0 + f0; acc[1] = e1 + f1;
                lsl2 += acc;
            }
            P0 = __builtin_bit_cast(bf16x8, B0);
            P1 = __builtin_bit_cast(bf16x8, B1);
        }
        {
            bf16x8 v0 = load_bf16x8(Vb + 0 * 512 + lane * 8);
            bf16x8 v1 = load_bf16x8(Vb + 1 * 512 + lane * 8);
            bf16x8 v2 = load_bf16x8(Vb + 2 * 512 + lane * 8);
            bf16x8 v3 = load_bf16x8(Vb + 3 * 512 + lane * 8);
            o0 = __builtin_amdgcn_mfma_f32_32x32x16_bf16(v0, P0, o0, 0, 0, 0);
            o1 = __builtin_amdgcn_mfma_f32_32x32x16_bf16(v1, P0, o1, 0, 0, 0);
            o0 = __builtin_amdgcn_mfma_f32_32x32x16_bf16(v2, P1, o0, 0, 0, 0);
            o1 = __builtin_amdgcn_mfma_f32_32x32x16_bf16(v3, P1, o1, 0, 0, 0);
        }
        // half 1: exp(sbp) -> P2,P3 ; PV chunks 4..7
        bf16x8 P2, P3;
        {
            u32x4 B0, B1;
            #pragma unroll
            for (int i = 0; i < 4; ++i) {
                float e0 = hw_exp2(sbp[2 * i]),     e1 = hw_exp2(sbp[2 * i + 1]);
                float f0 = hw_exp2(sbp[8 + 2 * i]), f1 = hw_exp2(sbp[8 + 2 * i + 1]);
                B0[i] = cvtpk2(e0, e1);
                B1[i] = cvtpk2(f0, f1);
                f32x2 acc; acc[0] = e0 + f0; acc[1] = e1 + f1;
                lsl2 += acc;
            }
            P2 = __builtin_bit_cast(bf16x8, B0);
            P3 = __builtin_bit_cast(bf16x8, B1);
        }
        {
            bf16x8 v4 = load_bf16x8(Vb + 4 * 512 + lane * 8);
            bf16x8 v5 = load_bf16x8(Vb + 5 * 512 + lane * 8);
            bf16x8 v6 = load_bf16x8(Vb + 6 * 512 + lane * 8);
            bf16x8 v7 = load_bf16x8(Vb + 7 * 512 + lane * 8);
            o0 = __builtin_amdgcn_mfma_f32_32x32x16_bf16(v4, P2, o0, 0, 0, 0);
            o1 = __builtin_amdgcn_mfma_f32_32x32x16_bf16(v5, P2, o1, 0, 0, 0);
            o0 = __builtin_amdgcn_mfma_f32_32x32x16_bf16(v6, P3, o0, 0, 0, 0);
            o1 = __builtin_amdgcn_mfma_f32_32x32x16_bf16(v7, P3, o1, 0, 0, 0);
        }
    }
    __syncthreads();   // buf reads done; stage(t+1) drained
}

__global__ __launch_bounds__(256, 3) void flash_attn_kernel(
    const __bf16* __restrict__ Qw, const __bf16* __restrict__ Kf,
    const __bf16* __restrict__ Vf, const float* __restrict__ amask,
    float* __restrict__ out)
{
    __shared__ __align__(16) FlashLds u;     // 40960 B
    __shared__ __bf16 mdd[SEQ];              // 4096 B -> 45056 total

    const int tid  = threadIdx.x;
    const int lane = tid & 63;
    const int w    = tid >> 6;
    const int n32  = lane & 31;
    const int hi   = lane >> 5;

    const int bid  = blockIdx.x;          // 768
    const int xcd  = bid & 7;
    const int slot = bid >> 3;            // 0..95
    const int bh   = xcd * 6 + (slot >> 4);
    const int qblk = slot & 15;
    const int b_   = bh / NH;
    const int h    = bh % NH;
    const int q0   = qblk * 128 + w * 32; // wave-owned 32 rows

    // mask -> log2-domain additive term (block-wide fill; fenced by first sync)
    const float* mp = amask + (size_t)b_ * SEQ;
    #pragma unroll
    for (int i = 0; i < 8; ++i) {
        const int idx = w * 512 + i * 64 + lane;
        mdd[idx] = (__bf16)fmaf(mp[idx], MASK_L2, -MASK_L2);
    }

    // Q as B-operand: B[k=16*dstep+8*hi+j][q=n32]
    const __bf16* Qrow = Qw + ((size_t)bh * SEQ + q0 + n32) * HD + 8 * hi;
    bf16x8 qf[4];
    #pragma unroll
    for (int d = 0; d < 4; ++d) qf[d] = load_bf16x8(Qrow + d * 16);

    bf16x8 qone;
    #pragma unroll
    for (int j = 0; j < 8; ++j) qone[j] = (__bf16)0.0f;
    if (hi == 0) qone[0] = (__bf16)1.0f;   // B[k=0][q] = 1

    // staging: waves 0,1 -> K halves; waves 2,3 -> V halves
    const size_t bhoff = (size_t)bh * SEQ * HD;
    const __bf16* gsrc = (w < 2 ? Kf : Vf) + bhoff + (w & 1) * 2048 + (size_t)lane * 8;

    // prologue: stage tile 0 -> k[0], v[0]
    {
        __bf16* dst = (w < 2) ? &u.s.k[0][0] + (w & 1) * 2048
                              : &u.s.v[0][0] + (w & 1) * 2048;
        #pragma unroll
        for (int c = 0; c < 4; ++c) async16(gsrc + c * 512, dst + c * 512);
    }
    __syncthreads();   // tile 0 + mdd ready

    f32x16 o0 = {0,0,0,0,0,0,0,0,0,0,0,0,0,0,0,0};
    f32x16 o1 = {0,0,0,0,0,0,0,0,0,0,0,0,0,0,0,0};
    f32x2 lsl2 = {0.f, 0.f};
    f32x16 saA, sbA, saB, sbB;

    // t=0: stage tile1 -> k[1],v[1]; S(0) -> A set; no PV yet
    fbody<0, true, false>(0, 0, 1, w, lane, n32, &u, mdd, gsrc,
                          qf, qone, saA, sbA, saA, sbA, o0, o1, lsl2);

    int vprev = 0, vnext = 2;
    #pragma unroll 1
    for (int tp = 0; tp < 15; ++tp) {
        const int t = 2 * tp + 1;
        fbody<1, true, true>(t, vprev, vnext, w, lane, n32, &u, mdd, gsrc,
                             qf, qone, saA, sbA, saB, sbB, o0, o1, lsl2);
        vprev = rot3(vprev); vnext = rot3(vnext);
        fbody<0, true, true>(t + 1, vprev, vnext, w, lane, n32, &u, mdd, gsrc,
                             qf, qone, saB, sbB, saA, sbA, o0, o1, lsl2);
        vprev = rot3(vprev); vnext = rot3(vnext);
    }
    // t=31 (no stage): S(31) -> B set; exp+PV(30) from v[0]
    fbody<1, false, true>(31, vprev, 0, w, lane, n32, &u, mdd, gsrc,
                          qf, qone, saA, sbA, saB, sbB, o0, o1, lsl2);

    // epilogue PV for tile 31: S in (saB,sbB), V(31) in v[1]
    {
        const __bf16* Vb = &u.s.v[1][0];
        bf16x8 P0, P1, P2, P3;
        {
            u32x4 B0, B1;
            #pragma unroll
            for (int i = 0; i < 4; ++i) {
                float e0 = hw_exp2(saB[2 * i]),     e1 = hw_exp2(saB[2 * i + 1]);
                float f0 = hw_exp2(saB[8 + 2 * i]), f1 = hw_exp2(saB[8 + 2 * i + 1]);
                B0[i] = cvtpk2(e0, e1); B1[i] = cvtpk2(f0, f1);
                f32x2 acc; acc[0] = e0 + f0; acc[1] = e1 + f1;
                lsl2 += acc;
            }
            P0 = __builtin_bit_cast(bf16x8, B0);
            P1 = __builtin_bit_cast(bf16x8, B1);
        }
        {
            u32x4 B0, B1;
            #pragma unroll
            for (int i = 0; i < 4; ++i) {
                float e0 = hw_exp2(sbB[2 * i]),     e1 = hw_exp2(sbB[2 * i + 1]);
                float f0 = hw_exp2(sbB[8 + 2 * i]), f1 = hw_exp2(sbB[8 + 2 * i + 1]);
                B0[i] = cvtpk2(e0, e1); B1[i] = cvtpk2(f0, f1);
                f32x2 acc; acc[0] = e0 + f0; acc[1] = e1 + f1;
                lsl2 += acc;
            }
            P2 = __builtin_bit_cast(bf16x8, B0);
            P3 = __builtin_bit_cast(bf16x8, B1);
        }
        #pragma unroll
        for (int c = 0; c < 4; ++c) {
            bf16x8 va = load_bf16x8(Vb + (2 * c) * 512 + lane * 8);
            bf16x8 vb = load_bf16x8(Vb + (2 * c + 1) * 512 + lane * 8);
            const bf16x8 P = c == 0 ? P0 : (c == 1 ? P1 : (c == 2 ? P2 : P3));
            o0 = __builtin_amdgcn_mfma_f32_32x32x16_bf16(va, P, o0, 0, 0, 0);
            o1 = __builtin_amdgcn_mfma_f32_32x32x16_bf16(vb, P, o1, 0, 0, 0);
        }
    }

    // complete row sums, in-register (q = n32 on lanes n32 and n32+32)
    float rs = lsl2[0] + lsl2[1];
    rs += __shfl_xor(rs, 32);

    __syncthreads();   // all K/V LDS reads done before et overwrites the union

    // per-wave transpose via et
    #pragma unroll
    for (int k = 0; k < 4; ++k) {
        f32x4 t0, t1;
        #pragma unroll
        for (int j = 0; j < 4; ++j) { t0[j] = o0[4 * k + j]; t1[j] = o1[4 * k + j]; }
        *(f32x4*)&u.et[w][n32][8 * k + 4 * hi]      = t0;   // d = j+8k+4hi
        *(f32x4*)&u.et[w][n32][32 + 8 * k + 4 * hi] = t1;   // d+32
    }
    // wave-local read-back
    const int d0 = (lane & 7) * 8;
    #pragma unroll
    for (int pass = 0; pass < 4; ++pass) {
        const int q = pass * 8 + (lane >> 3);
        const float linv = 1.0f / __shfl(rs, q);
        const float* er = &u.et[w][q][d0];
        f32x4 r0 = *(const f32x4*)(er);
        f32x4 r1 = *(const f32x4*)(er + 4);
        #pragma unroll
        for (int i = 0; i < 4; ++i) { r0[i] *= linv; r1[i] *= linv; }
        float* orow = out + ((size_t)b_ * SEQ + q0 + q) * NP + h * HD + d0;
        *(f32x4*)(orow)     = r0;
        *(f32x4*)(orow + 4) = r1;
    }
}

extern "C" void kernel_launch(void* const* d_in, const int* in_sizes, int n_in,
                              void* d_out, int out_size, void* d_ws, size_t ws_size,
                              hipStream_t stream) {
    const float* hidden = (const float*)d_in[0];
    const float* amask  = (const float*)d_in[1];
    const float* Wq     = (const float*)d_in[2];
    const float* bq     = (const float*)d_in[3];
    const float* Wk     = (const float*)d_in[4];
    const float* bk     = (const float*)d_in[5];
    const float* Wv     = (const float*)d_in[6];
    const float* bv     = (const float*)d_in[7];
    float* out = (float*)d_out;

    const size_t elems = (size_t)NB * NH * SEQ * HD; // 6,291,456
    __bf16* Qw = (__bf16*)d_ws;
    __bf16* Kf = Qw + elems;
    __bf16* Vf = Kf + elems;
    __bf16* Wt = Vf + elems;                 // 3*768*64 bf16 = 294,912 B
    float*  bt = (float*)(Wt + (size_t)3 * NP * 64);   // 3*768 f32

    wprep_kernel<<<dim3(36), 256, 0, stream>>>(Wq, Wk, Wv, bq, bk, bv, Wt, bt);

    qkv_kernel<<<dim3(128, 6), 256, 0, stream>>>(hidden, Wt, bt, Qw, Kf, Vf);

    flash_attn_kernel<<<dim3(768), 256, 0, stream>>>(
        Qw, Kf, Vf, amask, out);
}

// Round 6
// 151.869 us; speedup vs baseline: 1.0867x; 1.0867x over previous
//
#include <hip/hip_runtime.h>
#include <hip/hip_bf16.h>

#define NH 12
#define HD 64
#define NB 4
#define SEQ 2048
#define NP 768
#define LOG2E 1.44269504f
#define MASK_L2 14426.9504f   // 10000 * log2(e)

typedef __bf16 bf16x8 __attribute__((ext_vector_type(8)));
typedef __bf16 bf16x2 __attribute__((ext_vector_type(2)));
typedef float f32x2 __attribute__((ext_vector_type(2)));
typedef float f32x4 __attribute__((ext_vector_type(4)));
typedef float f32x16 __attribute__((ext_vector_type(16)));
typedef unsigned u32x4 __attribute__((ext_vector_type(4)));

static __device__ __forceinline__ bf16x8 load_bf16x8(const __bf16* p) {
    return *reinterpret_cast<const bf16x8*>(p);
}
static __device__ __forceinline__ float hw_exp2(float x) {
    return __builtin_amdgcn_exp2f(x);
}
// packed f32x2 -> bf16x2 (backend can select v_cvt_pk_bf16_f32 on gfx950)
static __device__ __forceinline__ unsigned cvtpk2(float lo, float hi) {
    f32x2 t; t[0] = lo; t[1] = hi;
    return __builtin_bit_cast(unsigned, __builtin_convertvector(t, bf16x2));
}
// async global->LDS, 16B per lane; LDS dest = uniform base + lane*16 (HW rule)
static __device__ __forceinline__ void async16(const __bf16* g, __bf16* l) {
    __builtin_amdgcn_global_load_lds(
        (const __attribute__((address_space(1))) unsigned*)(g),
        (__attribute__((address_space(3))) unsigned*)(l), 16, 0, 0);
}

// ---------------------------------------------------------------------------
// Kernel 1: QKV projection (REVERTED to the proven R0-R2 version: the wprep
// split regressed the non-flash residual 90 -> 101 us; wprep's 36-block
// strided-load transpose serialized on the critical path).
// Vf in SIGMA-PERMUTED key order sigma(8*hi+j) = (j&3)+8*(j>>2)+4*hi.
// ---------------------------------------------------------------------------
__global__ __launch_bounds__(256) void qkv_kernel(
    const float* __restrict__ hidden,
    const float* __restrict__ Wq, const float* __restrict__ Wk,
    const float* __restrict__ Wv,
    const float* __restrict__ bq, const float* __restrict__ bk,
    const float* __restrict__ bv,
    __bf16* __restrict__ Qw, __bf16* __restrict__ Kf, __bf16* __restrict__ Vf)
{
    __shared__ __bf16 wtileT[64][72];   // [c][k]
    __shared__ __bf16 ot[64][72];       // [t][c]

    const int tid  = threadIdx.x;
    const int lane = tid & 63;
    const int w    = tid >> 6;
    const int g    = lane >> 4;
    const int n    = lane & 15;
    const int n32  = lane & 31;
    const int hi   = lane >> 5;

    const int row0 = blockIdx.x * 64;
    const int gi   = blockIdx.y;          // 0..5
    const int b_   = row0 >> 11;
    const int t0   = row0 & (SEQ - 1);
    const int kb64 = t0 >> 6;

    const float* hrow = hidden + (size_t)(row0 + w * 16 + n) * HD + 8 * g;
    f32x4 h0 = *(const f32x4*)(hrow);
    f32x4 h1 = *(const f32x4*)(hrow + 4);
    f32x4 h2 = *(const f32x4*)(hrow + 32);
    f32x4 h3 = *(const f32x4*)(hrow + 36);
    bf16x8 a0, a1;
    #pragma unroll
    for (int j = 0; j < 4; ++j) {
        a0[j]     = (__bf16)h0[j];
        a0[j + 4] = (__bf16)h1[j];
        a1[j]     = (__bf16)h2[j];
        a1[j + 4] = (__bf16)h3[j];
    }

    const int dr   = tid >> 2;        // 0..63 (W row = k)
    const int coff = (tid & 3) * 16;  // 16 consecutive cols

    for (int tt = 0; tt < 6; ++tt) {
        const int tile_id = gi * 6 + tt;       // 0..35
        const int proj    = tile_id / 12;
        const int head    = tile_id % 12;
        const int bh      = b_ * NH + head;
        const float* W    = proj == 0 ? Wq : (proj == 1 ? Wk : Wv);
        const float* bias = proj == 0 ? bq : (proj == 1 ? bk : bv);
        const float qs    = (proj == 0) ? 0.125f * LOG2E : 1.0f;

        const float* wr = W + (size_t)dr * NP + head * 64 + coff;
        f32x4 x0 = *(const f32x4*)(wr);
        f32x4 x1 = *(const f32x4*)(wr + 4);
        f32x4 x2 = *(const f32x4*)(wr + 8);
        f32x4 x3 = *(const f32x4*)(wr + 12);
        #pragma unroll
        for (int i = 0; i < 4; ++i) {
            wtileT[coff + i     ][dr] = (__bf16)(x0[i] * qs);
            wtileT[coff + 4 + i ][dr] = (__bf16)(x1[i] * qs);
            wtileT[coff + 8 + i ][dr] = (__bf16)(x2[i] * qs);
            wtileT[coff + 12 + i][dr] = (__bf16)(x3[i] * qs);
        }
        __syncthreads();   // wtileT ready; also fences prev tile's ot reads

        #pragma unroll
        for (int dt = 0; dt < 4; ++dt) {
            const bf16x8 b0 = *(const bf16x8*)&wtileT[dt * 16 + n][8 * g];
            const bf16x8 b1 = *(const bf16x8*)&wtileT[dt * 16 + n][32 + 8 * g];
            f32x4 acc = {0.f, 0.f, 0.f, 0.f};
            acc = __builtin_amdgcn_mfma_f32_16x16x32_bf16(a0, b0, acc, 0, 0, 0);
            acc = __builtin_amdgcn_mfma_f32_16x16x32_bf16(a1, b1, acc, 0, 0, 0);
            const float bb = bias[head * 64 + dt * 16 + n] * qs;
            #pragma unroll
            for (int r = 0; r < 4; ++r)
                ot[w * 16 + 4 * g + r][dt * 16 + n] = (__bf16)(acc[r] + bb);
        }
        __syncthreads();   // ot complete; wtileT frag reads done

        if (proj == 0) {
            __bf16* dst = Qw + ((size_t)bh * SEQ + t0 + w * 16) * HD;
            const int tr = lane >> 2;
            const int d0 = (lane & 3) * 16;
            *(bf16x8*)(dst + (size_t)tr * HD + d0)     = *(const bf16x8*)&ot[w * 16 + tr][d0];
            *(bf16x8*)(dst + (size_t)tr * HD + d0 + 8) = *(const bf16x8*)&ot[w * 16 + tr][d0 + 8];
        } else if (proj == 1) {
            __bf16* base = Kf + (size_t)bh * SEQ * HD + (size_t)kb64 * 4096;
            #pragma unroll
            for (int sub = 0; sub < 2; ++sub) {
                const bf16x8 fr = *(const bf16x8*)&ot[sub * 32 + n32][w * 16 + 8 * hi];
                *(bf16x8*)(base + (size_t)(w * 2 + sub) * 512 + lane * 8) = fr;
            }
        } else {
            __bf16* base = Vf + (size_t)bh * SEQ * HD + (size_t)kb64 * 4096;
            #pragma unroll
            for (int dsub = 0; dsub < 2; ++dsub) {
                bf16x8 v;
                #pragma unroll
                for (int j = 0; j < 8; ++j)
                    v[j] = ot[w * 16 + ((j & 3) + 8 * (j >> 2) + 4 * hi)][dsub * 32 + n32];
                *(bf16x8*)(base + (size_t)(w * 2 + dsub) * 512 + lane * 8) = v;
            }
        }
    }
}

// ---------------------------------------------------------------------------
// Kernel 2 v16: v15 + data-dependent mask skip. Per 64-key group, a ballot
// during the mdd fill records "mask all ones"; when set, fbody skips the two
// mask-add MFMAs (11% of matrix issue) + their operand setup behind a
// readfirstlane-uniform branch. Numerically identical (skipped MFMAs add 0);
// general masks take the full path.
// ---------------------------------------------------------------------------
struct KVbuf {
    __bf16 k[2][4096];   // 16 KB
    __bf16 v[3][4096];   // 24 KB
};

union FlashLds {
    KVbuf s;                  // 40960 B
    float et[4][32][68];      // 34816 B (epilogue reuse)
};

static __device__ __forceinline__ int rot3(int x) { return x + 1 == 3 ? 0 : x + 1; }

// One pipelined iteration. KS = t&1 (K slot). STG: stage tile t+1. DOPV:
// run exp(t-1)+PV(t-1) from (sap,sbp) and v[vprev].
template<int KS, bool STG, bool DOPV>
static __device__ __forceinline__ void fbody(
    int t, int vprev, int vnext, int w, int lane, int n32,
    FlashLds* u, const __bf16* mdd, const unsigned* fl, const __bf16* gsrc,
    const bf16x8 (&qf)[4], const bf16x8& qone,
    f32x16& sap, f32x16& sbp, f32x16& san, f32x16& sbn,
    f32x16& o0, f32x16& o1, f32x2& lsl2)
{
    if (STG) {
        __bf16* dst = (w < 2) ? &u->s.k[KS ^ 1][0] + (w & 1) * 2048
                              : &u->s.v[vnext][0] + (w & 1) * 2048;
        const __bf16* src = gsrc + (size_t)(t + 1) * 4096;
        #pragma unroll
        for (int c = 0; c < 4; ++c) async16(src + c * 512, dst + c * 512);
    }

    // K(t) fragments
    const __bf16* Kb = &u->s.k[KS][0];
    bf16x8 kca[4], kcb[4];
    #pragma unroll
    for (int d = 0; d < 4; ++d) {
        kca[d] = load_bf16x8(Kb + (2 * d) * 512 + lane * 8);
        kcb[d] = load_bf16x8(Kb + (2 * d + 1) * 512 + lane * 8);
    }

    // S(t) burst (new accumulators; prev set stays live for exp below)
    f32x16 z = {0,0,0,0,0,0,0,0,0,0,0,0,0,0,0,0};
    san = z; sbn = z;
    #pragma unroll
    for (int d = 0; d < 4; ++d)
        san = __builtin_amdgcn_mfma_f32_32x32x16_bf16(kca[d], qf[d], san, 0, 0, 0);
    #pragma unroll
    for (int d = 0; d < 4; ++d)
        sbn = __builtin_amdgcn_mfma_f32_32x32x16_bf16(kcb[d], qf[d], sbn, 0, 0, 0);

    // mask add: skipped (uniform branch) when this 64-key group is all-ones
    if (__builtin_amdgcn_readfirstlane(fl[t]) == 0u) {
        const int kb = t << 6;
        bf16x8 maa, mab;
        #pragma unroll
        for (int j = 0; j < 8; ++j) { maa[j] = (__bf16)0.0f; mab[j] = (__bf16)0.0f; }
        maa[0] = mdd[kb + n32];
        mab[0] = mdd[kb + 32 + n32];
        san = __builtin_amdgcn_mfma_f32_32x32x16_bf16(maa, qone, san, 0, 0, 0);
        sbn = __builtin_amdgcn_mfma_f32_32x32x16_bf16(mab, qone, sbn, 0, 0, 0);
    }

    if (DOPV) {
        const __bf16* Vb = &u->s.v[vprev][0];
        // half 0: exp(sap) -> P0,P1 ; PV chunks 0..3
        bf16x8 P0, P1;
        {
            u32x4 B0, B1;
            #pragma unroll
            for (int i = 0; i < 4; ++i) {
                float e0 = hw_exp2(sap[2 * i]),     e1 = hw_exp2(sap[2 * i + 1]);
                float f0 = hw_exp2(sap[8 + 2 * i]), f1 = hw_exp2(sap[8 + 2 * i + 1]);
                B0[i] = cvtpk2(e0, e1);
                B1[i] = cvtpk2(f0, f1);
                f32x2 acc; acc[0] = e0 + f0; acc[1] = e1 + f1;
                lsl2 += acc;
            }
            P0 = __builtin_bit_cast(bf16x8, B0);
            P1 = __builtin_bit_cast(bf16x8, B1);
        }
        {
            bf16x8 v0 = load_bf16x8(Vb + 0 * 512 + lane * 8);
            bf16x8 v1 = load_bf16x8(Vb + 1 * 512 + lane * 8);
            bf16x8 v2 = load_bf16x8(Vb + 2 * 512 + lane * 8);
            bf16x8 v3 = load_bf16x8(Vb + 3 * 512 + lane * 8);
            o0 = __builtin_amdgcn_mfma_f32_32x32x16_bf16(v0, P0, o0, 0, 0, 0);
            o1 = __builtin_amdgcn_mfma_f32_32x32x16_bf16(v1, P0, o1, 0, 0, 0);
            o0 = __builtin_amdgcn_mfma_f32_32x32x16_bf16(v2, P1, o0, 0, 0, 0);
            o1 = __builtin_amdgcn_mfma_f32_32x32x16_bf16(v3, P1, o1, 0, 0, 0);
        }
        // half 1: exp(sbp) -> P2,P3 ; PV chunks 4..7
        bf16x8 P2, P3;
        {
            u32x4 B0, B1;
            #pragma unroll
            for (int i = 0; i < 4; ++i) {
                float e0 = hw_exp2(sbp[2 * i]),     e1 = hw_exp2(sbp[2 * i + 1]);
                float f0 = hw_exp2(sbp[8 + 2 * i]), f1 = hw_exp2(sbp[8 + 2 * i + 1]);
                B0[i] = cvtpk2(e0, e1);
                B1[i] = cvtpk2(f0, f1);
                f32x2 acc; acc[0] = e0 + f0; acc[1] = e1 + f1;
                lsl2 += acc;
            }
            P2 = __builtin_bit_cast(bf16x8, B0);
            P3 = __builtin_bit_cast(bf16x8, B1);
        }
        {
            bf16x8 v4 = load_bf16x8(Vb + 4 * 512 + lane * 8);
            bf16x8 v5 = load_bf16x8(Vb + 5 * 512 + lane * 8);
            bf16x8 v6 = load_bf16x8(Vb + 6 * 512 + lane * 8);
            bf16x8 v7 = load_bf16x8(Vb + 7 * 512 + lane * 8);
            o0 = __builtin_amdgcn_mfma_f32_32x32x16_bf16(v4, P2, o0, 0, 0, 0);
            o1 = __builtin_amdgcn_mfma_f32_32x32x16_bf16(v5, P2, o1, 0, 0, 0);
            o0 = __builtin_amdgcn_mfma_f32_32x32x16_bf16(v6, P3, o0, 0, 0, 0);
            o1 = __builtin_amdgcn_mfma_f32_32x32x16_bf16(v7, P3, o1, 0, 0, 0);
        }
    }
    __syncthreads();   // buf reads done; stage(t+1) drained
}

__global__ __launch_bounds__(256, 3) void flash_attn_kernel(
    const __bf16* __restrict__ Qw, const __bf16* __restrict__ Kf,
    const __bf16* __restrict__ Vf, const float* __restrict__ amask,
    float* __restrict__ out)
{
    __shared__ __align__(16) FlashLds u;     // 40960 B
    __shared__ __bf16 mdd[SEQ];              // 4096 B
    __shared__ unsigned fl[32];              // per-64-key "all ones" flags

    const int tid  = threadIdx.x;
    const int lane = tid & 63;
    const int w    = tid >> 6;
    const int n32  = lane & 31;
    const int hi   = lane >> 5;

    const int bid  = blockIdx.x;          // 768
    const int xcd  = bid & 7;
    const int slot = bid >> 3;            // 0..95
    const int bh   = xcd * 6 + (slot >> 4);
    const int qblk = slot & 15;
    const int b_   = bh / NH;
    const int h    = bh % NH;
    const int q0   = qblk * 128 + w * 32; // wave-owned 32 rows

    // mask -> log2-domain additive term + all-ones flags (fenced by 1st sync)
    const float* mp = amask + (size_t)b_ * SEQ;
    #pragma unroll
    for (int i = 0; i < 8; ++i) {
        const int idx = w * 512 + i * 64 + lane;
        const float m = mp[idx];
        mdd[idx] = (__bf16)fmaf(m, MASK_L2, -MASK_L2);
        const unsigned long long bl = __ballot(m == 1.0f);
        if (lane == 0) fl[w * 8 + i] = (bl == ~0ULL) ? 1u : 0u;
    }

    // Q as B-operand: B[k=16*dstep+8*hi+j][q=n32]
    const __bf16* Qrow = Qw + ((size_t)bh * SEQ + q0 + n32) * HD + 8 * hi;
    bf16x8 qf[4];
    #pragma unroll
    for (int d = 0; d < 4; ++d) qf[d] = load_bf16x8(Qrow + d * 16);

    bf16x8 qone;
    #pragma unroll
    for (int j = 0; j < 8; ++j) qone[j] = (__bf16)0.0f;
    if (hi == 0) qone[0] = (__bf16)1.0f;   // B[k=0][q] = 1

    // staging: waves 0,1 -> K halves; waves 2,3 -> V halves
    const size_t bhoff = (size_t)bh * SEQ * HD;
    const __bf16* gsrc = (w < 2 ? Kf : Vf) + bhoff + (w & 1) * 2048 + (size_t)lane * 8;

    // prologue: stage tile 0 -> k[0], v[0]
    {
        __bf16* dst = (w < 2) ? &u.s.k[0][0] + (w & 1) * 2048
                              : &u.s.v[0][0] + (w & 1) * 2048;
        #pragma unroll
        for (int c = 0; c < 4; ++c) async16(gsrc + c * 512, dst + c * 512);
    }
    __syncthreads();   // tile 0 + mdd + fl ready

    f32x16 o0 = {0,0,0,0,0,0,0,0,0,0,0,0,0,0,0,0};
    f32x16 o1 = {0,0,0,0,0,0,0,0,0,0,0,0,0,0,0,0};
    f32x2 lsl2 = {0.f, 0.f};
    f32x16 saA, sbA, saB, sbB;

    // t=0: stage tile1 -> k[1],v[1]; S(0) -> A set; no PV yet
    fbody<0, true, false>(0, 0, 1, w, lane, n32, &u, mdd, fl, gsrc,
                          qf, qone, saA, sbA, saA, sbA, o0, o1, lsl2);

    int vprev = 0, vnext = 2;
    #pragma unroll 1
    for (int tp = 0; tp < 15; ++tp) {
        const int t = 2 * tp + 1;
        fbody<1, true, true>(t, vprev, vnext, w, lane, n32, &u, mdd, fl, gsrc,
                             qf, qone, saA, sbA, saB, sbB, o0, o1, lsl2);
        vprev = rot3(vprev); vnext = rot3(vnext);
        fbody<0, true, true>(t + 1, vprev, vnext, w, lane, n32, &u, mdd, fl, gsrc,
                             qf, qone, saB, sbB, saA, sbA, o0, o1, lsl2);
        vprev = rot3(vprev); vnext = rot3(vnext);
    }
    // t=31 (no stage): S(31) -> B set; exp+PV(30) from v[0]
    fbody<1, false, true>(31, vprev, 0, w, lane, n32, &u, mdd, fl, gsrc,
                          qf, qone, saA, sbA, saB, sbB, o0, o1, lsl2);

    // epilogue PV for tile 31: S in (saB,sbB), V(31) in v[1]
    {
        const __bf16* Vb = &u.s.v[1][0];
        bf16x8 P0, P1, P2, P3;
        {
            u32x4 B0, B1;
            #pragma unroll
            for (int i = 0; i < 4; ++i) {
                float e0 = hw_exp2(saB[2 * i]),     e1 = hw_exp2(saB[2 * i + 1]);
                float f0 = hw_exp2(saB[8 + 2 * i]), f1 = hw_exp2(saB[8 + 2 * i + 1]);
                B0[i] = cvtpk2(e0, e1); B1[i] = cvtpk2(f0, f1);
                f32x2 acc; acc[0] = e0 + f0; acc[1] = e1 + f1;
                lsl2 += acc;
            }
            P0 = __builtin_bit_cast(bf16x8, B0);
            P1 = __builtin_bit_cast(bf16x8, B1);
        }
        {
            u32x4 B0, B1;
            #pragma unroll
            for (int i = 0; i < 4; ++i) {
                float e0 = hw_exp2(sbB[2 * i]),     e1 = hw_exp2(sbB[2 * i + 1]);
                float f0 = hw_exp2(sbB[8 + 2 * i]), f1 = hw_exp2(sbB[8 + 2 * i + 1]);
                B0[i] = cvtpk2(e0, e1); B1[i] = cvtpk2(f0, f1);
                f32x2 acc; acc[0] = e0 + f0; acc[1] = e1 + f1;
                lsl2 += acc;
            }
            P2 = __builtin_bit_cast(bf16x8, B0);
            P3 = __builtin_bit_cast(bf16x8, B1);
        }
        #pragma unroll
        for (int c = 0; c < 4; ++c) {
            bf16x8 va = load_bf16x8(Vb + (2 * c) * 512 + lane * 8);
            bf16x8 vb = load_bf16x8(Vb + (2 * c + 1) * 512 + lane * 8);
            const bf16x8 P = c == 0 ? P0 : (c == 1 ? P1 : (c == 2 ? P2 : P3));
            o0 = __builtin_amdgcn_mfma_f32_32x32x16_bf16(va, P, o0, 0, 0, 0);
            o1 = __builtin_amdgcn_mfma_f32_32x32x16_bf16(vb, P, o1, 0, 0, 0);
        }
    }

    // complete row sums, in-register (q = n32 on lanes n32 and n32+32)
    float rs = lsl2[0] + lsl2[1];
    rs += __shfl_xor(rs, 32);

    __syncthreads();   // all K/V LDS reads done before et overwrites the union

    // per-wave transpose via et
    #pragma unroll
    for (int k = 0; k < 4; ++k) {
        f32x4 t0, t1;
        #pragma unroll
        for (int j = 0; j < 4; ++j) { t0[j] = o0[4 * k + j]; t1[j] = o1[4 * k + j]; }
        *(f32x4*)&u.et[w][n32][8 * k + 4 * hi]      = t0;   // d = j+8k+4hi
        *(f32x4*)&u.et[w][n32][32 + 8 * k + 4 * hi] = t1;   // d+32
    }
    // wave-local read-back
    const int d0 = (lane & 7) * 8;
    #pragma unroll
    for (int pass = 0; pass < 4; ++pass) {
        const int q = pass * 8 + (lane >> 3);
        const float linv = 1.0f / __shfl(rs, q);
        const float* er = &u.et[w][q][d0];
        f32x4 r0 = *(const f32x4*)(er);
        f32x4 r1 = *(const f32x4*)(er + 4);
        #pragma unroll
        for (int i = 0; i < 4; ++i) { r0[i] *= linv; r1[i] *= linv; }
        float* orow = out + ((size_t)b_ * SEQ + q0 + q) * NP + h * HD + d0;
        *(f32x4*)(orow)     = r0;
        *(f32x4*)(orow + 4) = r1;
    }
}

extern "C" void kernel_launch(void* const* d_in, const int* in_sizes, int n_in,
                              void* d_out, int out_size, void* d_ws, size_t ws_size,
                              hipStream_t stream) {
    const float* hidden = (const float*)d_in[0];
    const float* amask  = (const float*)d_in[1];
    const float* Wq     = (const float*)d_in[2];
    const float* bq     = (const float*)d_in[3];
    const float* Wk     = (const float*)d_in[4];
    const float* bk     = (const float*)d_in[5];
    const float* Wv     = (const float*)d_in[6];
    const float* bv     = (const float*)d_in[7];
    float* out = (float*)d_out;

    const size_t elems = (size_t)NB * NH * SEQ * HD; // 6,291,456
    __bf16* Qw = (__bf16*)d_ws;
    __bf16* Kf = Qw + elems;
    __bf16* Vf = Kf + elems;

    qkv_kernel<<<dim3(128, 6), 256, 0, stream>>>(
        hidden, Wq, Wk, Wv, bq, bk, bv, Qw, Kf, Vf);

    flash_attn_kernel<<<dim3(768), 256, 0, stream>>>(
        Qw, Kf, Vf, amask, out);
}